// Round 15
// baseline (122.777 us; speedup 1.0000x reference)
//
#include <hip/hip_runtime.h>
#include <math.h>

#define NP 4
#define NN 8192  // cam points per part (lane-owned "targets")
#define NM 8192  // cad points per part (broadcast "queries")

// grid (QS, TS, NP) x 256 threads; block: QB cad-queries x SLAB cam-targets
#define QS 64    // query splits (PB slice count)
#define QB 128   // queries per block (8192/QS)
#define TS 2     // target slabs (PA slice count)
#define TT 16    // cam targets per thread (held in registers)
#define SLAB 4096  // targets per block (256*TT); TS*SLAB = 8192

#define BIAS 1024.0f  // DPP 0-fill guard: all biased minA values < 0

// ws layout (float units): partial min slices, unique writer per slot.
#define PA_OFF 0                     // [TS][NP*NM]  cad-side mins (d^2/2)
#define PB_OFF (TS * NP * NM)        // [QS][NP*NN]  cam-side mins (d^2/2)
// total: (2 + 64) * 32768 floats = 8.65 MB

typedef float float2v __attribute__((ext_vector_type(2)));

__device__ inline float min3f(float a, float b, float c) {
    float d;
    asm("v_min3_f32 %0, %1, %2, %3" : "=v"(d) : "v"(a), "v"(b), "v"(c));
    return d;
}
__device__ inline float2v pk_fma(float2v a, float2v b, float2v c) {
    float2v d;
    asm("v_pk_fma_f32 %0, %1, %2, %3" : "=v"(d) : "v"(a), "v"(b), "v"(c));
    return d;
}
__device__ inline float2v pk_add(float2v a, float2v b) {
    float2v d;
    asm("v_pk_add_f32 %0, %1, %2" : "=v"(d) : "v"(a), "v"(b));
    return d;
}

// Wave64 min via DPP (VALU only, no LDS). Requires all values < 0 so the
// bound_ctrl 0-fill acts as +inf identity. Result lands in lane 63.
#define DPP_MIN(r, ctrl)                                                     \
    r = fminf(r, __uint_as_float((unsigned)__builtin_amdgcn_update_dpp(      \
                     0, (int)__float_as_uint(r), (ctrl), 0xf, 0xf, true)))

__device__ inline void make_transform(const float* __restrict__ quat,
                                      const float* __restrict__ tra,
                                      int p, float T[12]) {
    float q0 = quat[p * 4 + 0], q1 = quat[p * 4 + 1];
    float q2 = quat[p * 4 + 2], q3 = quat[p * 4 + 3];
    float inv = 1.0f / sqrtf(q0 * q0 + q1 * q1 + q2 * q2 + q3 * q3);
    float a = q0 * inv, b = q1 * inv, c = q2 * inv, d = q3 * inv;
    T[0] = 1.0f - 2.0f * c * c - 2.0f * d * d;
    T[1] = 2.0f * b * c - 2.0f * a * d;
    T[2] = 2.0f * a * c + 2.0f * b * d;
    T[3] = tra[p * 3 + 0];
    T[4] = 2.0f * b * c + 2.0f * a * d;
    T[5] = 1.0f - 2.0f * b * b - 2.0f * d * d;
    T[6] = 2.0f * c * d - 2.0f * a * b;
    T[7] = tra[p * 3 + 1];
    T[8] = 2.0f * b * d - 2.0f * a * c;
    T[9] = 2.0f * a * b + 2.0f * c * d;
    T[10] = 1.0f - 2.0f * b * b - 2.0f * c * c;
    T[11] = tra[p * 3 + 2];
}

// Fused single-pass chamfer: transforms computed in-block (no prep kernel),
// each (a,b) pair evaluated ONCE serving both directions.
//   u = h_a - a.b  (3 pk_fma per 2 targets, query scalars duplicated)
//   minB[b] = h_b + min_a u      (per-lane registers; h_b added at store --
//                                 R14 FAILED because this term was dropped)
//   minA[a] = min_b (u + h_b)    (h_b pre-biased by -BIAS; DPP wave-reduce,
//                                 LDS merge across the 4 waves)
// Partials stored to private slices (no atomics, no init).
__global__ __launch_bounds__(256, 2) void chamfer_kernel(
    const float* __restrict__ cam, const float* __restrict__ cad,
    const float* __restrict__ quat, const float* __restrict__ tra,
    float* __restrict__ ws, float* __restrict__ out) {
    int tid = threadIdx.x;
    int lane = tid & 63;
    int wv = tid >> 6;
    int qb = blockIdx.x;   // query split  -> PB slice index
    int ts = blockIdx.y;   // target slab  -> PA slice index
    int p = blockIdx.z;
    const float INF = __uint_as_float(0x7f800000u);

    __shared__ float4 sQ[QB];        // staged queries: (-x,-y,-z, h_a)
    __shared__ float sMA[4 * QB];    // per-wave minA partials (biased)

    // --- setup: stage+transform QB cad queries (threads 0..127) ---
    if (tid < QB) {
        float T[12];
        make_transform(quat, tra, p, T);
        int g = p * NM + qb * QB + tid;
        float x = cad[g * 3 + 0], y = cad[g * 3 + 1], z = cad[g * 3 + 2];
        float vx = fmaf(T[0], x, fmaf(T[1], y, fmaf(T[2], z, T[3])));
        float vy = fmaf(T[4], x, fmaf(T[5], y, fmaf(T[6], z, T[7])));
        float vz = fmaf(T[8], x, fmaf(T[9], y, fmaf(T[10], z, T[11])));
        float h = 0.5f * (vx * vx + vy * vy + vz * vz);
        sQ[tid] = make_float4(-vx, -vy, -vz, h);
    } else if (qb == 0 && ts == 0 && p == 0) {
        // spare threads of block (0,0,0): emit transforms + zero objective
        int t2 = tid - QB;
        if (t2 < 64) {
            int p2 = t2 >> 4, r = (t2 >> 2) & 3, c = t2 & 3;
            float T[12];
            make_transform(quat, tra, p2, T);
            out[1 + t2] = (r == 3) ? ((c == 3) ? 1.0f : 0.0f) : T[r * 4 + c];
        } else if (t2 == 64) {
            out[0] = 0.0f;
        }
    }

    // --- setup: load TT cam targets into registers (pk-paired) ---
    float2v TX[TT / 2], TY[TT / 2], TZ[TT / 2], THb[TT / 2];
    float fminB[TT];
#pragma unroll
    for (int j = 0; j < TT; ++j) {
        int n = ts * SLAB + j * 256 + tid;          // within-part cam index
        int g = p * NN + n;
        float bx = cam[g * 3 + 0], by = cam[g * 3 + 1], bz = cam[g * 3 + 2];
        float hb = 0.5f * (bx * bx + by * by + bz * bz);
        TX[j >> 1][j & 1] = bx;
        TY[j >> 1][j & 1] = by;
        TZ[j >> 1][j & 1] = bz;
        THb[j >> 1][j & 1] = hb - BIAS;             // pre-biased for DPP
        fminB[j] = INF;
    }
    __syncthreads();

    // --- main loop: QB queries x (64 lanes * TT targets) per wave ---
#pragma unroll 2
    for (int q = 0; q < QB; ++q) {
        float4 qv = sQ[q];  // ds_read_b128, broadcast (conflict-free)
        float2v nx = {qv.x, qv.x};
        float2v ny = {qv.y, qv.y};
        float2v nz = {qv.z, qv.z};
        float2v ah = {qv.w, qv.w};
        float m = 0.0f;  // biased values are < 0, so 0 == +inf identity
#pragma unroll
        for (int i = 0; i < TT / 2; ++i) {
            float2v u = pk_fma(nx, TX[i], pk_fma(ny, TY[i], pk_fma(nz, TZ[i], ah)));
            fminB[2 * i] = fminf(fminB[2 * i], u[0]);
            fminB[2 * i + 1] = fminf(fminB[2 * i + 1], u[1]);
            float2v wb = pk_add(u, THb[i]);  // biased d^2/2
            m = min3f(m, wb[0], wb[1]);
        }
        // wave-min via DPP: row_shr 1/2/4/8, row_bcast 15/31 -> lane 63
        DPP_MIN(m, 0x111);
        DPP_MIN(m, 0x112);
        DPP_MIN(m, 0x114);
        DPP_MIN(m, 0x118);
        DPP_MIN(m, 0x142);
        DPP_MIN(m, 0x143);
        float red = __uint_as_float(
            (unsigned)__builtin_amdgcn_readlane(__float_as_uint(m), 63));
        if (lane == 0) sMA[wv * QB + q] = red;
    }
    __syncthreads();

    // --- endgame: private-slice partial stores (coalesced, no atomics) ---
    if (tid < QB) {
        float va = fminf(fminf(sMA[tid], sMA[QB + tid]),
                         fminf(sMA[2 * QB + tid], sMA[3 * QB + tid]));
        ws[PA_OFF + ts * (NP * NM) + p * NM + qb * QB + tid] = va + BIAS;
    }
#pragma unroll
    for (int j = 0; j < TT; ++j) {
        int n = ts * SLAB + j * 256 + tid;
        float hb = THb[j >> 1][j & 1] + BIAS;  // restore h_b (R14's bug)
        ws[PB_OFF + qb * (NP * NN) + p * NN + n] = fminB[j] + hb;
    }
}

// 128 blocks x 256: merge slices, sqrt, weight, reduce.
__global__ __launch_bounds__(256) void finalize_kernel(
    const float* __restrict__ ws, const float* __restrict__ w,
    float* __restrict__ out) {
    int i = blockIdx.x * 256 + threadIdx.x;  // [0, 32768)
    int tid = threadIdx.x;
    const float INF = __uint_as_float(0x7f800000u);

    float va = INF;
#pragma unroll
    for (int s = 0; s < TS; ++s) va = fminf(va, ws[PA_OFF + s * (NP * NM) + i]);
    float vb = INF;
#pragma unroll 8
    for (int s = 0; s < QS; ++s) vb = fminf(vb, ws[PB_OFF + s * (NP * NN) + i]);

    float wp = w[(i >> 13) & 3];
    float acc = wp * (sqrtf(fmaxf(2.0f * va, 0.0f)) +
                      sqrtf(fmaxf(2.0f * vb, 0.0f)));

#pragma unroll
    for (int off = 32; off > 0; off >>= 1) acc += __shfl_down(acc, off, 64);

    __shared__ float wsum[4];
    if ((tid & 63) == 0) wsum[tid >> 6] = acc;
    __syncthreads();
    if (tid == 0) {
        float blocksum = (wsum[0] + wsum[1] + wsum[2] + wsum[3]) * (1.0f / 8192.0f);
        atomicAdd(out, blocksum);
    }
}

extern "C" void kernel_launch(void* const* d_in, const int* in_sizes, int n_in,
                              void* d_out, int out_size, void* d_ws, size_t ws_size,
                              hipStream_t stream) {
    const float* cam = (const float*)d_in[0];   // (P, N, 3)
    const float* cad = (const float*)d_in[1];   // (P, M, 3)
    const float* w = (const float*)d_in[2];     // (P,)
    const float* quat = (const float*)d_in[3];  // (P, 4)
    const float* tra = (const float*)d_in[4];   // (P, 3, 1)
    float* out = (float*)d_out;
    float* ws = (float*)d_ws;

    dim3 grid(QS, TS, NP);
    chamfer_kernel<<<grid, 256, 0, stream>>>(cam, cad, quat, tra, ws, out);

    finalize_kernel<<<128, 256, 0, stream>>>(ws, w, out);
}